// Round 9
// baseline (111.584 us; speedup 1.0000x reference)
//
#include <hip/hip_runtime.h>
#include <hip/hip_fp16.h>
#include <math.h>

#define NE 16
#define HD 1024
#define FD 2048

typedef _Float16 half2v __attribute__((ext_vector_type(2)));

// ws layout (4-byte units)
#define TOPI_OFF 0          // 256 int
#define TOPW_OFF 256        // 256 float
#define CNT_OFF  512        // 16 int
#define PREF_OFF 528        // 16 int
#define SLOT_OFF 544        // 256 int (pair -> slot)
#define INVT_OFF 800        // 256 int (slot -> token)
#define XH_OFF   4096                   // xh fp16 [256][1024] = 131072 ints
#define HBUF_OFF (XH_OFF + 131072)      // h  fp16 [256][2048] = 262144 ints
#define Y_OFF    (HBUF_OFF + 262144)    // y  f32  [256][1024]

#if __has_builtin(__builtin_amdgcn_fdot2)
#define FDOT2(a, b, c) __builtin_amdgcn_fdot2(a, b, c, false)
#else
__device__ __forceinline__ float FDOT2(half2v a, half2v b, float c) {
    return fmaf((float)a.x, (float)b.x, fmaf((float)a.y, (float)b.y, c));
}
#endif

// fp4 e2m1 nibble -> fp16 bits (unscaled)
__device__ __forceinline__ int fp4h(int nib) {
    int c = nib & 7;
    int v;
    if (c == 0) v = 0;
    else if (c == 1) v = 14 << 10;                        // 0.5
    else v = (((c >> 1) + 14) << 10) | ((c & 1) << 9);
    v |= (nib & 8) << 12;
    return v;
}

// LUT byte -> 2 packed fp16 times packed pow2 scale (exact)
__device__ __forceinline__ half2v dec2(const int* lut, int byte, int sv) {
    int l = lut[byte & 255];
    __half2 p = *reinterpret_cast<const __half2*>(&l);
    __half2 sc = *reinterpret_cast<const __half2*>(&sv);
    __half2 r = __hmul2(p, sc);
    return *reinterpret_cast<half2v*>(&r);
}

union XF { int4 v; half2v h[4]; };

// paired-merge butterfly: 16 per-lane partials -> per-token totals; lane L gets token (L>>2)
__device__ __forceinline__ float reduce16(const float* v, int lane) {
    float r8[8];
    #pragma unroll
    for (int i = 0; i < 8; ++i) {
        bool hi = lane & 32;
        float keep = hi ? v[i + 8] : v[i];
        float send = hi ? v[i] : v[i + 8];
        r8[i] = keep + __shfl_xor(send, 32);
    }
    float r4[4];
    #pragma unroll
    for (int i = 0; i < 4; ++i) {
        bool hi = lane & 16;
        float keep = hi ? r8[i + 4] : r8[i];
        float send = hi ? r8[i] : r8[i + 4];
        r4[i] = keep + __shfl_xor(send, 16);
    }
    float r2[2];
    #pragma unroll
    for (int i = 0; i < 2; ++i) {
        bool hi = lane & 8;
        float keep = hi ? r4[i + 2] : r4[i];
        float send = hi ? r4[i] : r4[i + 2];
        r2[i] = keep + __shfl_xor(send, 8);
    }
    bool hi = lane & 4;
    float keep = hi ? r2[1] : r2[0];
    float send = hi ? r2[0] : r2[1];
    float r = keep + __shfl_xor(send, 4);
    r += __shfl_xor(r, 2);
    r += __shfl_xor(r, 1);
    return r;
}

// 8 partials -> totals; lane L gets token (L>>3)
__device__ __forceinline__ float reduce8(const float* v, int lane) {
    float r4[4];
    #pragma unroll
    for (int i = 0; i < 4; ++i) {
        bool hi = lane & 32;
        float keep = hi ? v[i + 4] : v[i];
        float send = hi ? v[i] : v[i + 4];
        r4[i] = keep + __shfl_xor(send, 32);
    }
    float r2[2];
    #pragma unroll
    for (int i = 0; i < 2; ++i) {
        bool hi = lane & 16;
        float keep = hi ? r2 /*dummy*/[0] * 0.f + r4[i + 2] : r4[i];   // avoid self-ref; real code below
        (void)keep;
        float k2 = (lane & 16) ? r4[i + 2] : r4[i];
        float s2 = (lane & 16) ? r4[i] : r4[i + 2];
        r2[i] = k2 + __shfl_xor(s2, 16);
    }
    bool hi = lane & 8;
    float keep = hi ? r2[1] : r2[0];
    float send = hi ? r2[0] : r2[1];
    float r = keep + __shfl_xor(send, 8);
    r += __shfl_xor(r, 4);
    r += __shfl_xor(r, 2);
    r += __shfl_xor(r, 1);
    return r;
}

__global__ void routing_kernel(const float* __restrict__ x, const float* __restrict__ rw,
                               int* __restrict__ top_idx, float* __restrict__ top_w) {
    int t = blockIdx.x;
    int tid = threadIdx.x;          // 256
    int e = tid >> 4, seg = tid & 15;
    const float* xr = x + t * HD + seg * 64;
    const float* wr = rw + e * HD + seg * 64;
    float p = 0.f;
    #pragma unroll 8
    for (int i = 0; i < 64; ++i) p += xr[i] * wr[i];
    __shared__ float part[16][16];
    __shared__ float logit[16];
    part[e][seg] = p;
    __syncthreads();
    if (tid < 16) {
        float s = 0.f;
        #pragma unroll
        for (int i = 0; i < 16; ++i) s += part[tid][i];
        logit[tid] = s;
    }
    __syncthreads();
    if (tid == 0) {
        int i0 = 0; float v0 = logit[0];
        #pragma unroll
        for (int i = 1; i < 16; ++i) { if (logit[i] > v0) { v0 = logit[i]; i0 = i; } }
        int i1 = -1; float v1 = -1e30f;
        #pragma unroll
        for (int i = 0; i < 16; ++i) { if (i != i0 && logit[i] > v1) { v1 = logit[i]; i1 = i; } }
        float w0 = 1.f / (1.f + expf(v1 - v0));
        float w1 = 1.f / (1.f + expf(v0 - v1));
        top_idx[t * 2]     = i0;  top_w[t * 2]     = w0;
        top_idx[t * 2 + 1] = i1;  top_w[t * 2 + 1] = w1;
    }
}

__global__ void build_kernel(const int* __restrict__ top_idx,
                             int* __restrict__ cnt, int* __restrict__ pref,
                             int* __restrict__ slot, int* __restrict__ invtok) {
    __shared__ int scnt[16], spref[16], scur[16];
    int tid = threadIdx.x;          // 256
    if (tid < 16) scnt[tid] = 0;
    __syncthreads();
    int e = top_idx[tid];
    atomicAdd(&scnt[e], 1);
    __syncthreads();
    if (tid == 0) {
        int s = 0;
        for (int i = 0; i < 16; ++i) { spref[i] = s; pref[i] = s; cnt[i] = scnt[i]; s += scnt[i]; }
    }
    if (tid < 16) scur[tid] = 0;
    __syncthreads();
    int pos = spref[e] + atomicAdd(&scur[e], 1);
    slot[tid] = pos;
    invtok[pos] = tid >> 1;
}

__global__ void gather_kernel(const float* __restrict__ x, const int* __restrict__ invtok,
                              _Float16* __restrict__ xh) {
    int slt = blockIdx.x;           // 256
    int t = invtok[slt];
    int i = threadIdx.x;            // 256 threads x 4 elems
    float4 v = ((const float4*)(x + (long)t * HD))[i];
    union { _Float16 h[4]; int2 p; } o;
    o.h[0] = (_Float16)v.x; o.h[1] = (_Float16)v.y;
    o.h[2] = (_Float16)v.z; o.h[3] = (_Float16)v.w;
    ((int2*)(xh + (long)slt * HD))[i] = o.p;
}

// gu GEMM + SwiGLU, token-resident registers / streamed weights.
// Wave: 16 tokens x k-slice [lane*16, lane*16+16); streams 8 f (gate+up row pairs).
__global__ __launch_bounds__(256, 2) void gemm1_stream(
    const _Float16* __restrict__ xh, const int* __restrict__ qblk,
    const int* __restrict__ qscl, const float* __restrict__ bias,
    const int* __restrict__ cnt, const int* __restrict__ pref,
    _Float16* __restrict__ hbuf) {
    int bid = blockIdx.x;
    int e = bid >> 9;
    int mt = (bid >> 6) & 7;
    int fblk = bid & 63;
    int n = cnt[e];
    if (mt * 16 >= n) return;
    int nt = n - mt * 16; if (nt > 16) nt = 16;
    __shared__ int lut[256];
    int tid = threadIdx.x;
    lut[tid] = fp4h(tid & 15) | (fp4h(tid >> 4) << 16);
    __syncthreads();
    int wave = tid >> 6, lane = tid & 63;
    int base = pref[e];
    int t0 = base + mt * 16;

    XF xa[16], xb[16];                 // 128 VGPRs of token data - must stay resident
    #pragma unroll
    for (int t = 0; t < 16; ++t) {
        int tt = t < nt ? t : nt - 1;
        const int4* xr = (const int4*)(xh + (long)(t0 + tt) * HD) + lane * 2;
        xa[t].v = xr[0];
        xb[t].v = xr[1];
    }

    int f0 = fblk * 32 + wave * 8;
    long rg0 = (long)e * 4096 + f0;

    for (int fi = 0; fi < 8; ++fi) {
        long rg = rg0 + fi;            // gate row
        long ru = rg + FD;             // up row
        // ---- gate ----
        int scg = qscl[rg * 32 + (lane >> 1)];
        int svg = (scg - 112) << 10; svg |= svg << 16;
        const int4* wpg = (const int4*)(qblk + rg * 512) + lane * 2;
        int4 g0 = wpg[0], g1 = wpg[1];
        half2v wg[8];
        wg[0] = dec2(lut, g0.x, svg); wg[1] = dec2(lut, g0.y, svg);
        wg[2] = dec2(lut, g0.z, svg); wg[3] = dec2(lut, g0.w, svg);
        wg[4] = dec2(lut, g1.x, svg); wg[5] = dec2(lut, g1.y, svg);
        wg[6] = dec2(lut, g1.z, svg); wg[7] = dec2(lut, g1.w, svg);
        float accg[16];
        #pragma unroll
        for (int t = 0; t < 16; ++t) {
            float a = 0.f;
            #pragma unroll
            for (int i = 0; i < 4; ++i) {
                a = FDOT2(wg[i],     xa[t].h[i], a);
                a = FDOT2(wg[i + 4], xb[t].h[i], a);
            }
            accg[t] = a;
        }
        float rgv = reduce16(accg, lane);
        // ---- up ----
        int scu = qscl[ru * 32 + (lane >> 1)];
        int svu = (scu - 112) << 10; svu |= svu << 16;
        const int4* wpu = (const int4*)(qblk + ru * 512) + lane * 2;
        int4 u0 = wpu[0], u1 = wpu[1];
        half2v wu[8];
        wu[0] = dec2(lut, u0.x, svu); wu[1] = dec2(lut, u0.y, svu);
        wu[2] = dec2(lut, u0.z, svu); wu[3] = dec2(lut, u0.w, svu);
        wu[4] = dec2(lut, u1.x, svu); wu[5] = dec2(lut, u1.y, svu);
        wu[6] = dec2(lut, u1.z, svu); wu[7] = dec2(lut, u1.w, svu);
        float accu[16];
        #pragma unroll
        for (int t = 0; t < 16; ++t) {
            float a = 0.f;
            #pragma unroll
            for (int i = 0; i < 4; ++i) {
                a = FDOT2(wu[i],     xa[t].h[i], a);
                a = FDOT2(wu[i + 4], xb[t].h[i], a);
            }
            accu[t] = a;
        }
        float ruv = reduce16(accu, lane);
        // epilogue: lane 4*t holds token t's totals
        if ((lane & 3) == 0) {
            int t = lane >> 2;
            if (t < nt) {
                float g = rgv + bias[rg];
                float u = ruv + bias[ru];
                float h = (g / (1.f + expf(-g))) * u;
                hbuf[(long)(t0 + t) * FD + f0 + fi] = (_Float16)(h * 0.0625f);  // 2^-4 exact
            }
        }
    }
}

// down GEMM, token-resident / streamed weights. Wave: 8 tokens x k-slice
// [lane*32, lane*32+32); streams 8 h rows.
__global__ __launch_bounds__(256, 2) void gemm2_stream(
    const _Float16* __restrict__ hbuf, const int* __restrict__ qblk,
    const int* __restrict__ qscl, const float* __restrict__ bias,
    const int* __restrict__ cnt, const int* __restrict__ pref,
    float* __restrict__ y) {
    int bid = blockIdx.x;
    int e = bid >> 9;
    int mt = (bid >> 5) & 15;
    int hblk = bid & 31;
    int n = cnt[e];
    if (mt * 8 >= n) return;
    int nt = n - mt * 8; if (nt > 8) nt = 8;
    __shared__ int lut[256];
    int tid = threadIdx.x;
    lut[tid] = fp4h(tid & 15) | (fp4h(tid >> 4) << 16);
    __syncthreads();
    int wave = tid >> 6, lane = tid & 63;
    int base = pref[e];
    int t0 = base + mt * 8;

    XF xc[8][4];                       // 128 VGPRs of token data
    #pragma unroll
    for (int t = 0; t < 8; ++t) {
        int tt = t < nt ? t : nt - 1;
        const int4* xr = (const int4*)(hbuf + (long)(t0 + tt) * FD) + lane * 4;
        xc[t][0].v = xr[0]; xc[t][1].v = xr[1];
        xc[t][2].v = xr[2]; xc[t][3].v = xr[3];
    }

    int h0 = hblk * 32 + wave * 8;
    long r0 = (long)e * HD + h0;

    for (int hi = 0; hi < 8; ++hi) {
        long r = r0 + hi;
        int sc = qscl[r * 64 + lane];
        int sv = (sc - 112) << 10; sv |= sv << 16;
        const int4* wp = (const int4*)(qblk + r * 1024) + lane * 4;
        half2v w[16];
        #pragma unroll
        for (int q = 0; q < 4; ++q) {
            int4 qq = wp[q];
            w[q * 4 + 0] = dec2(lut, qq.x, sv);
            w[q * 4 + 1] = dec2(lut, qq.y, sv);
            w[q * 4 + 2] = dec2(lut, qq.z, sv);
            w[q * 4 + 3] = dec2(lut, qq.w, sv);
        }
        float acc[8];
        #pragma unroll
        for (int t = 0; t < 8; ++t) {
            float a = 0.f;
            #pragma unroll
            for (int q = 0; q < 4; ++q) {
                a = FDOT2(w[q * 4 + 0], xc[t][q].h[0], a);
                a = FDOT2(w[q * 4 + 1], xc[t][q].h[1], a);
                a = FDOT2(w[q * 4 + 2], xc[t][q].h[2], a);
                a = FDOT2(w[q * 4 + 3], xc[t][q].h[3], a);
            }
            acc[t] = a;
        }
        float rv = reduce8(acc, lane);
        if ((lane & 7) == 0) {
            int t = lane >> 3;
            if (t < nt)
                y[(long)(t0 + t) * HD + h0 + hi] = rv * 16.f + bias[r];
        }
    }
}

__global__ void combine_kernel(const float* __restrict__ ybuf, const int* __restrict__ slot,
                               const float* __restrict__ topw, float* __restrict__ out) {
    int t = blockIdx.x;
    int i = threadIdx.x;   // 256, float4 each
    int s0 = slot[2 * t], s1 = slot[2 * t + 1];
    float w0 = topw[2 * t], w1 = topw[2 * t + 1];
    float4 a = ((const float4*)(ybuf + (long)s0 * HD))[i];
    float4 b = ((const float4*)(ybuf + (long)s1 * HD))[i];
    float4 o;
    o.x = w0 * a.x + w1 * b.x;
    o.y = w0 * a.y + w1 * b.y;
    o.z = w0 * a.z + w1 * b.z;
    o.w = w0 * a.w + w1 * b.w;
    ((float4*)(out + (long)t * HD))[i] = o;
}

extern "C" void kernel_launch(void* const* d_in, const int* in_sizes, int n_in,
                              void* d_out, int out_size, void* d_ws, size_t ws_size,
                              hipStream_t stream) {
    const float* x          = (const float*)d_in[0];
    const float* rw         = (const float*)d_in[1];
    const float* bias_gu    = (const float*)d_in[2];
    const float* bias_down  = (const float*)d_in[3];
    const int*   blocks_gu  = (const int*)d_in[4];
    const int*   scales_gu  = (const int*)d_in[5];
    const int*   blocks_down= (const int*)d_in[6];
    const int*   scales_down= (const int*)d_in[7];
    float* out = (float*)d_out;
    int*   wsI = (int*)d_ws;
    float* wsF = (float*)d_ws;
    _Float16* xh   = (_Float16*)(wsI + XH_OFF);
    _Float16* hbuf = (_Float16*)(wsI + HBUF_OFF);
    float*    y    = wsF + Y_OFF;

    routing_kernel<<<128, 256, 0, stream>>>(x, rw, wsI + TOPI_OFF, wsF + TOPW_OFF);
    build_kernel<<<1, 256, 0, stream>>>(wsI + TOPI_OFF, wsI + CNT_OFF, wsI + PREF_OFF,
                                        wsI + SLOT_OFF, wsI + INVT_OFF);
    gather_kernel<<<256, 256, 0, stream>>>(x, wsI + INVT_OFF, xh);
    gemm1_stream<<<NE * 512, 256, 0, stream>>>(xh, blocks_gu, scales_gu, bias_gu,
                                               wsI + CNT_OFF, wsI + PREF_OFF, hbuf);
    gemm2_stream<<<NE * 512, 256, 0, stream>>>(hbuf, blocks_down, scales_down, bias_down,
                                               wsI + CNT_OFF, wsI + PREF_OFF, y);
    combine_kernel<<<128, 256, 0, stream>>>(y, wsI + SLOT_OFF, wsF + TOPW_OFF, out);
}